// Round 4
// baseline (3300.263 us; speedup 1.0000x reference)
//
#include <hip/hip_runtime.h>
#include <hip/hip_bf16.h>

// AttenDecoder: B=64 T=32 S=64 E=128 H=256 V=32000.
// I/O is fp32 (per reference dtypes); compute uses bf16 MFMA with fp32 accum.
// Pipeline: gather/convert X -> MFMA GEMM gi -> convert Whh/Winw to bf16 ->
// per-batch GRU+attn recurrence (64 blocks x 1024 threads, eo[b] in LDS,
// bf16 weight streams) -> MFMA GEMM relu-logits -> in-place log_softmax.

typedef __attribute__((ext_vector_type(8))) short  s8v;
typedef __attribute__((ext_vector_type(8))) __bf16 bf8v;
typedef __attribute__((ext_vector_type(4))) float  f4v;
typedef __attribute__((ext_vector_type(2))) float  f2v;

#define DEV static __device__ __forceinline__

DEV ushort f2b(float f) {            // round-to-nearest-even fp32 -> bf16
  unsigned u = __float_as_uint(f);
  u += 0x7fffu + ((u >> 16) & 1u);
  return (ushort)(u >> 16);
}
DEV float b2fs(short s) { return __uint_as_float(((unsigned)(ushort)s) << 16); }

// ---------------------------------------------------------------- gather X
// X[tb][640] = bf16([target[b,t,:], pos_feature[b,:], encoder_state[b,:], inp[b,t,:]])
__global__ __launch_bounds__(256) void k_gather(
    const float* __restrict__ target, const float* __restrict__ inp,
    const float* __restrict__ posf,   const float* __restrict__ encs,
    ushort* __restrict__ X) {
  int tb = blockIdx.x; int t = tb >> 6, b = tb & 63;
  size_t xrow = (size_t)tb * 640;
  for (int c = threadIdx.x; c < 640; c += 256) {
    float v;
    if (c < 128)      v = target[((size_t)b * 32 + t) * 128 + c];
    else if (c < 256) v = posf[(size_t)b * 128 + (c - 128)];
    else if (c < 512) v = encs[(size_t)b * 256 + (c - 256)];
    else              v = inp[((size_t)b * 32 + t) * 128 + (c - 512)];
    X[xrow + c] = f2b(v);
  }
}

// ----------------------------------------- weight convert fp32 -> bf16
// Wb[0:196608] = bf16(Whh), Wb[196608:327680] = bf16(Winw).
// Runs after gemm#1 (overwrites the then-dead X region of ws).
__global__ __launch_bounds__(256) void k_wconv(
    const float* __restrict__ Whh, const float* __restrict__ Winw,
    ushort* __restrict__ Wb) {
  int i = blockIdx.x * 256 + threadIdx.x;
  float v = (i < 196608) ? Whh[i] : Winw[i - 196608];
  Wb[i] = f2b(v);
}

// ------------------------------------------------- MFMA GEMM, B^T layout
// C[m,n] = sum_k A[m,k]*B[n,k] + bias[n].  A bf16 (ws), B fp32 (input weights,
// converted to bf16 in-register during staging).  128x128 tile, BK=32, 4 waves,
// each wave 64x64 via 4x4 of 16x16x32 bf16 MFMA.  LDS rows padded 32->40.
template <bool RELU>
__global__ __launch_bounds__(256) void k_gemm_bt(
    const ushort* __restrict__ A, const float* __restrict__ B,
    const float* __restrict__ bias, float* __restrict__ Out,
    int N, int K) {
  __shared__ __align__(16) ushort As[128 * 40];
  __shared__ __align__(16) ushort Bs[128 * 40];
  const int m0 = blockIdx.x * 128, n0 = blockIdx.y * 128;  // x=M: consecutive
  const int tid = threadIdx.x;                             // blocks share B-strip (L2)
  const int lane = tid & 63, wv = tid >> 6;
  const int wm = (wv >> 1) * 64, wn = (wv & 1) * 64;
  const int fr = lane & 15, fq = lane >> 4;
  const int srow = tid >> 2, scol = (tid & 3) * 8;
  f4v acc[4][4];
#pragma unroll
  for (int i = 0; i < 4; ++i)
#pragma unroll
    for (int j = 0; j < 4; ++j) acc[i][j] = {0.f, 0.f, 0.f, 0.f};
  const ushort* ag = A + (size_t)(m0 + srow) * K + scol;
  const float*  bg = B + (size_t)(n0 + srow) * K + scol;
  for (int k0 = 0; k0 < K; k0 += 32) {
    s8v a0 = *(const s8v*)(ag + k0);
    s8v a1 = *(const s8v*)(ag + k0 + (size_t)64 * K);
    f4v b00 = *(const f4v*)(bg + k0);
    f4v b01 = *(const f4v*)(bg + k0 + 4);
    f4v b10 = *(const f4v*)(bg + k0 + (size_t)64 * K);
    f4v b11 = *(const f4v*)(bg + k0 + (size_t)64 * K + 4);
    s8v b0, b1;
#pragma unroll
    for (int u = 0; u < 4; ++u) {
      b0[u]     = (short)f2b(b00[u]);
      b0[u + 4] = (short)f2b(b01[u]);
      b1[u]     = (short)f2b(b10[u]);
      b1[u + 4] = (short)f2b(b11[u]);
    }
    __syncthreads();
    *(s8v*)&As[srow * 40 + scol] = a0;
    *(s8v*)&As[(srow + 64) * 40 + scol] = a1;
    *(s8v*)&Bs[srow * 40 + scol] = b0;
    *(s8v*)&Bs[(srow + 64) * 40 + scol] = b1;
    __syncthreads();
    bf8v af[4], bfr[4];
#pragma unroll
    for (int i = 0; i < 4; ++i)
      af[i] = *(const bf8v*)&As[(wm + i * 16 + fr) * 40 + fq * 8];
#pragma unroll
    for (int j = 0; j < 4; ++j)
      bfr[j] = *(const bf8v*)&Bs[(wn + j * 16 + fr) * 40 + fq * 8];
#pragma unroll
    for (int i = 0; i < 4; ++i)
#pragma unroll
      for (int j = 0; j < 4; ++j)
        acc[i][j] = __builtin_amdgcn_mfma_f32_16x16x32_bf16(af[i], bfr[j],
                                                            acc[i][j], 0, 0, 0);
  }
  float bj[4];
#pragma unroll
  for (int j = 0; j < 4; ++j) bj[j] = bias[n0 + wn + j * 16 + fr];
#pragma unroll
  for (int i = 0; i < 4; ++i) {
#pragma unroll
    for (int j = 0; j < 4; ++j) {
#pragma unroll
      for (int r = 0; r < 4; ++r) {
        int gm = m0 + wm + i * 16 + fq * 4 + r;  // D row = quad*4+reg (m89)
        int gn = n0 + wn + j * 16 + fr;          // D col = lane&15
        float v = acc[i][j][r] + bj[j];
        if (RELU) v = fmaxf(v, 0.f);
        Out[(size_t)gm * N + gn] = v;
      }
    }
  }
}

// -------------------------------------------------------- recurrence
// One block per batch element b; all 32 timesteps inside the block.
// 1024 threads (16 waves, 4/SIMD).  eo[b] (128KB fp32) staged in LDS once.
// Weight streams (Whh, Winw) are pre-converted bf16: halves both the bytes
// and the load count per step (round-2 counters showed the weight sweep --
// 2.68GB fp32 demand, 40% L2 miss, latency-exposed -- was the whole cost).
__global__ __launch_bounds__(1024, 4) void k_recur(
    const float* __restrict__ gi_all,   // [32*64][768] (includes b_ih)
    const float* __restrict__ eo,       // [64][64][512] fp32
    const ushort* __restrict__ Whhb,    // [768][256] bf16
    const float* __restrict__ bhh,      // [768]
    const ushort* __restrict__ Winwb,   // [512][256] bf16
    const float* __restrict__ Winb,     // [512]
    ushort* __restrict__ feat,          // [32*64][768] bf16 out (GEMM A)
    float* __restrict__ hs_out) {       // [64][256] fp32 out (d_out base)
  const int b = blockIdx.x, tid = threadIdx.x;
  __shared__ __align__(16) float eoS[64 * 512];   // 128 KB
  __shared__ __align__(16) float h[256];
  __shared__ __align__(16) float q[512];
  __shared__ float attnp[64];
  __shared__ float score[64];
  const float* eoB = eo + (size_t)b * 32768;
  // stage eo[b] -> LDS, coalesced f4v
#pragma unroll
  for (int i = 0; i < 8; ++i) {
    int idx = i * 1024 + tid;
    *(f4v*)&eoS[idx * 4] = *(const f4v*)(eoB + (size_t)idx * 4);
  }

  // gh phase: hidden unit t = tid>>2, k-quarter lane p = tid&3 (interleaved,
  // 8-bf16 chunks: 4 lanes cover one 64B line per iter)
  const int t = tid >> 2, p = tid & 3;
  const ushort* wr = Whhb + (size_t)t * 256 + p * 8;
  const ushort* wz = wr + 65536;    // (t+256)*256
  const ushort* wn = wr + 131072;   // (t+512)*256
  const float bhr = bhh[t], bhz = bhh[t + 256], bhn = bhh[t + 512];

  // q phase: output qo = tid>>1, k-half lane qp = tid&1 (interleaved)
  const int qo = tid >> 1, qp = tid & 1;
  const ushort* wq = Winwb + (size_t)qo * 256 + qp * 8;
  const float qb = Winb[qo];

  // attn phase: score row as = tid>>4, k-slice lane aj = tid&15 (interleaved)
  const int as = tid >> 4, aj = tid & 15;

  if (tid < 256) h[tid] = 0.f;
  __syncthreads();

  for (int st = 0; st < 32; ++st) {
    const float* gi = gi_all + ((size_t)st * 64 + b) * 768;
    float g0 = gi[t], g1 = gi[t + 256], g2 = gi[t + 512];  // hoist: hide latency
    // ---- gh = h @ Whh.T (rows t, t+256, t+512), 4-way k-split, bf16 weights
    float ar = 0.f, az = 0.f, an = 0.f;
#pragma unroll
    for (int i = 0; i < 8; ++i) {
      s8v rv = *(const s8v*)(wr + i * 32);
      s8v zv = *(const s8v*)(wz + i * 32);
      s8v nv = *(const s8v*)(wn + i * 32);
      f4v h0 = *(const f4v*)&h[p * 8 + i * 32];
      f4v h1 = *(const f4v*)&h[p * 8 + i * 32 + 4];
      float hv[8] = {h0.x, h0.y, h0.z, h0.w, h1.x, h1.y, h1.z, h1.w};
#pragma unroll
      for (int u = 0; u < 8; ++u) {
        ar = fmaf(hv[u], b2fs(rv[u]), ar);
        az = fmaf(hv[u], b2fs(zv[u]), az);
        an = fmaf(hv[u], b2fs(nv[u]), an);
      }
    }
    ar += __shfl_xor(ar, 1); ar += __shfl_xor(ar, 2);
    az += __shfl_xor(az, 1); az += __shfl_xor(az, 2);
    an += __shfl_xor(an, 1); an += __shfl_xor(an, 2);
    float hnew = 0.f;
    if (p == 0) {
      float r = 1.f / (1.f + __expf(-(g0 + ar + bhr)));
      float z = 1.f / (1.f + __expf(-(g1 + az + bhz)));
      float e2 = __expf(2.f * (g2 + r * (an + bhn)));  // tanh, inf-safe
      float n = 1.f - 2.f / (e2 + 1.f);
      hnew = (1.f - z) * n + z * h[t];
    }
    __syncthreads();
    if (p == 0) h[t] = hnew;
    __syncthreads();
    // ---- q = h @ Winw.T + Winb, 2-way k-split, bf16 weights, dual accum
    float a0 = 0.f, a1 = 0.f;
#pragma unroll
    for (int i = 0; i < 8; ++i) {
      s8v w0 = *(const s8v*)(wq + i * 32);
      s8v w1 = *(const s8v*)(wq + i * 32 + 16);
      f4v h00 = *(const f4v*)&h[qp * 8 + i * 32];
      f4v h01 = *(const f4v*)&h[qp * 8 + i * 32 + 4];
      f4v h10 = *(const f4v*)&h[qp * 8 + i * 32 + 16];
      f4v h11 = *(const f4v*)&h[qp * 8 + i * 32 + 20];
      float hv0[8] = {h00.x, h00.y, h00.z, h00.w, h01.x, h01.y, h01.z, h01.w};
      float hv1[8] = {h10.x, h10.y, h10.z, h10.w, h11.x, h11.y, h11.z, h11.w};
#pragma unroll
      for (int u = 0; u < 8; ++u) {
        a0 = fmaf(hv0[u], b2fs(w0[u]), a0);
        a1 = fmaf(hv1[u], b2fs(w1[u]), a1);
      }
    }
    a0 += a1;
    a0 += __shfl_xor(a0, 1);
    if (qp == 0) q[qo] = a0 + qb;
    __syncthreads();
    // ---- attn[s] = eoS[s,:] . q  — 16 lanes per s, interleaved LDS chunks
    float aa = 0.f;
#pragma unroll
    for (int i = 0; i < 8; ++i) {
      int kk = aj * 4 + i * 64;
      f4v ev = *(const f4v*)&eoS[as * 512 + kk];
      f4v qv = *(const f4v*)&q[kk];
#pragma unroll
      for (int u = 0; u < 4; ++u) aa = fmaf(ev[u], qv[u], aa);
    }
    aa += __shfl_xor(aa, 1); aa += __shfl_xor(aa, 2);
    aa += __shfl_xor(aa, 4); aa += __shfl_xor(aa, 8);
    if (aj == 0) attnp[as] = aa;
    __syncthreads();
    if (tid < 64) {  // softmax over S=64, all inside wave 0
      float a = attnp[tid];
      float m = a;
#pragma unroll
      for (int off = 32; off > 0; off >>= 1) m = fmaxf(m, __shfl_xor(m, off));
      float e = __expf(a - m);
      float ss = e;
#pragma unroll
      for (int off = 32; off > 0; off >>= 1) ss += __shfl_xor(ss, off);
      score[tid] = e / ss;
    }
    __syncthreads();
    // ---- h_star[d] = sum_s score[s]*eoS[s,d]; feat = bf16([h_star, h])
    // d-pair = t (tid>>2), 4-way s-split lane p
    size_t row = ((size_t)st * 64 + b) * 768;
    {
      int d0 = 2 * t;
      float s0 = 0.f, s1 = 0.f;
#pragma unroll
      for (int i = 0; i < 16; ++i) {
        int s2 = p * 16 + i;
        float sc = score[s2];
        f2v ev = *(const f2v*)&eoS[s2 * 512 + d0];
        s0 = fmaf(sc, ev.x, s0);
        s1 = fmaf(sc, ev.y, s1);
      }
      s0 += __shfl_xor(s0, 1); s0 += __shfl_xor(s0, 2);
      s1 += __shfl_xor(s1, 1); s1 += __shfl_xor(s1, 2);
      if (p == 0) {
        feat[row + d0] = f2b(s0);
        feat[row + d0 + 1] = f2b(s1);
      }
    }
    if (tid < 256) feat[row + 512 + tid] = f2b(h[tid]);
    // no trailing barrier: next write to LDS (h) is behind two barriers
  }
  if (tid < 256) hs_out[(size_t)b * 256 + tid] = h[tid];
}

// ----------------------------------------------- in-place log_softmax (fp32)
// One block per (t,b) row of 32000 relu'd logits in d_out.
__global__ __launch_bounds__(256) void k_logsm(float* __restrict__ out) {
  float* p = out + (size_t)blockIdx.x * 32000;
  const int t = threadIdx.x;
  __shared__ float red[4];
  float m = 0.f;  // relu'd values are >= 0
  for (int c = t; c < 4000; c += 256) {
    f4v a = *(const f4v*)(p + (size_t)c * 8);
    f4v b = *(const f4v*)(p + (size_t)c * 8 + 4);
    m = fmaxf(m, fmaxf(fmaxf(a.x, a.y), fmaxf(a.z, a.w)));
    m = fmaxf(m, fmaxf(fmaxf(b.x, b.y), fmaxf(b.z, b.w)));
  }
#pragma unroll
  for (int off = 32; off > 0; off >>= 1) m = fmaxf(m, __shfl_xor(m, off));
  if ((t & 63) == 0) red[t >> 6] = m;
  __syncthreads();
  m = fmaxf(fmaxf(red[0], red[1]), fmaxf(red[2], red[3]));
  float s = 0.f;
  for (int c = t; c < 4000; c += 256) {
    f4v a = *(const f4v*)(p + (size_t)c * 8);
    f4v b = *(const f4v*)(p + (size_t)c * 8 + 4);
    s += __expf(a.x - m) + __expf(a.y - m) + __expf(a.z - m) + __expf(a.w - m);
    s += __expf(b.x - m) + __expf(b.y - m) + __expf(b.z - m) + __expf(b.w - m);
  }
#pragma unroll
  for (int off = 32; off > 0; off >>= 1) s += __shfl_xor(s, off);
  __syncthreads();
  if ((t & 63) == 0) red[t >> 6] = s;
  __syncthreads();
  s = red[0] + red[1] + red[2] + red[3];
  const float L = m + logf(s);
  for (int c = t; c < 4000; c += 256) {
    f4v a = *(const f4v*)(p + (size_t)c * 8);
    f4v b = *(const f4v*)(p + (size_t)c * 8 + 4);
    a.x -= L; a.y -= L; a.z -= L; a.w -= L;
    b.x -= L; b.y -= L; b.z -= L; b.w -= L;
    *(f4v*)(p + (size_t)c * 8) = a;
    *(f4v*)(p + (size_t)c * 8 + 4) = b;
  }
}

extern "C" void kernel_launch(void* const* d_in, const int* in_sizes, int n_in,
                              void* d_out, int out_size, void* d_ws, size_t ws_size,
                              hipStream_t stream) {
  (void)in_sizes; (void)n_in; (void)out_size; (void)ws_size;
  const float* target = (const float*)d_in[0];
  const float* inp    = (const float*)d_in[1];
  const float* posf   = (const float*)d_in[2];
  const float* encs   = (const float*)d_in[3];
  const float* enco   = (const float*)d_in[4];
  const float* Wih    = (const float*)d_in[5];
  const float* Whh    = (const float*)d_in[6];
  const float* bih    = (const float*)d_in[7];
  const float* bhh    = (const float*)d_in[8];
  const float* Winw   = (const float*)d_in[9];
  const float* Winb   = (const float*)d_in[10];
  const float* Woutw  = (const float*)d_in[11];
  const float* Woutb  = (const float*)d_in[12];

  char* ws = (char*)d_ws;
  ushort* X    = (ushort*)(ws);              // 2048*640  bf16 = 2.62 MB
  float*  gi   = (float*)(ws + 0x300000);    // 2048*768  fp32 = 6.29 MB
  ushort* feat = (ushort*)(ws + 0x900000);   // 2048*768  bf16 = 3.15 MB
  // bf16 weights overwrite the X region (dead after gemm#1): 640 KB < 2.62 MB
  ushort* Wb   = (ushort*)(ws);              // [768*256 Whh][512*256 Winw]
  ushort* Whhb = Wb;
  ushort* Winwb = Wb + 196608;
  float* hs    = (float*)d_out;              // [16384 hs][2048*32000 logits]
  float* logits = hs + 16384;

  k_gather<<<2048, 256, 0, stream>>>(target, inp, posf, encs, X);
  k_gemm_bt<false><<<dim3(16, 6), 256, 0, stream>>>(X, Wih, bih, gi, 768, 640);
  k_wconv<<<1280, 256, 0, stream>>>(Whh, Winw, Wb);
  k_recur<<<64, 1024, 0, stream>>>(gi, enco, Whhb, bhh, Winwb, Winb, feat, hs);
  k_gemm_bt<true><<<dim3(16, 250), 256, 0, stream>>>(feat, Woutw, Woutb, logits,
                                                     32000, 768);
  k_logsm<<<2048, 256, 0, stream>>>(logits);
}

// Round 6
// 2855.678 us; speedup vs baseline: 1.1557x; 1.1557x over previous
//
#include <hip/hip_runtime.h>
#include <hip/hip_bf16.h>

// AttenDecoder: B=64 T=32 S=64 E=128 H=256 V=32000.
// I/O is fp32 (per reference dtypes); compute uses bf16 MFMA with fp32 accum.
// Pipeline: gather/convert X -> MFMA GEMM gi -> per-batch-group GRU+attn
// recurrence (16 blocks x 1024 threads, 4 batches/block: each weight load
// feeds 4 fmaf chains -> 4x less weight traffic + 4x latency hiding) ->
// MFMA GEMM relu-logits -> in-place log_softmax.

typedef __attribute__((ext_vector_type(8))) short  s8v;
typedef __attribute__((ext_vector_type(8))) __bf16 bf8v;
typedef __attribute__((ext_vector_type(4))) float  f4v;
typedef __attribute__((ext_vector_type(2))) float  f2v;

#define DEV static __device__ __forceinline__

DEV ushort f2b(float f) {            // round-to-nearest-even fp32 -> bf16
  unsigned u = __float_as_uint(f);
  u += 0x7fffu + ((u >> 16) & 1u);
  return (ushort)(u >> 16);
}
DEV float b2fs(short s) { return __uint_as_float(((unsigned)(ushort)s) << 16); }

// ---------------------------------------------------------------- gather X
// X[tb][640] = bf16([target[b,t,:], pos_feature[b,:], encoder_state[b,:], inp[b,t,:]])
__global__ __launch_bounds__(256) void k_gather(
    const float* __restrict__ target, const float* __restrict__ inp,
    const float* __restrict__ posf,   const float* __restrict__ encs,
    ushort* __restrict__ X) {
  int tb = blockIdx.x; int t = tb >> 6, b = tb & 63;
  size_t xrow = (size_t)tb * 640;
  for (int c = threadIdx.x; c < 640; c += 256) {
    float v;
    if (c < 128)      v = target[((size_t)b * 32 + t) * 128 + c];
    else if (c < 256) v = posf[(size_t)b * 128 + (c - 128)];
    else if (c < 512) v = encs[(size_t)b * 256 + (c - 256)];
    else              v = inp[((size_t)b * 32 + t) * 128 + (c - 512)];
    X[xrow + c] = f2b(v);
  }
}

// ------------------------------------------------- MFMA GEMM, B^T layout
// C[m,n] = sum_k A[m,k]*B[n,k] + bias[n].  A bf16 (ws), B fp32 (input weights,
// converted to bf16 in-register during staging).  128x128 tile, BK=32, 4 waves,
// each wave 64x64 via 4x4 of 16x16x32 bf16 MFMA.  LDS rows padded 32->40.
template <bool RELU>
__global__ __launch_bounds__(256) void k_gemm_bt(
    const ushort* __restrict__ A, const float* __restrict__ B,
    const float* __restrict__ bias, float* __restrict__ Out,
    int N, int K) {
  __shared__ __align__(16) ushort As[128 * 40];
  __shared__ __align__(16) ushort Bs[128 * 40];
  const int m0 = blockIdx.x * 128, n0 = blockIdx.y * 128;  // x=M: consecutive
  const int tid = threadIdx.x;                             // blocks share B-strip (L2)
  const int lane = tid & 63, wv = tid >> 6;
  const int wm = (wv >> 1) * 64, wn = (wv & 1) * 64;
  const int fr = lane & 15, fq = lane >> 4;
  const int srow = tid >> 2, scol = (tid & 3) * 8;
  f4v acc[4][4];
#pragma unroll
  for (int i = 0; i < 4; ++i)
#pragma unroll
    for (int j = 0; j < 4; ++j) acc[i][j] = {0.f, 0.f, 0.f, 0.f};
  const ushort* ag = A + (size_t)(m0 + srow) * K + scol;
  const float*  bg = B + (size_t)(n0 + srow) * K + scol;
  for (int k0 = 0; k0 < K; k0 += 32) {
    s8v a0 = *(const s8v*)(ag + k0);
    s8v a1 = *(const s8v*)(ag + k0 + (size_t)64 * K);
    f4v b00 = *(const f4v*)(bg + k0);
    f4v b01 = *(const f4v*)(bg + k0 + 4);
    f4v b10 = *(const f4v*)(bg + k0 + (size_t)64 * K);
    f4v b11 = *(const f4v*)(bg + k0 + (size_t)64 * K + 4);
    s8v b0, b1;
#pragma unroll
    for (int u = 0; u < 4; ++u) {
      b0[u]     = (short)f2b(b00[u]);
      b0[u + 4] = (short)f2b(b01[u]);
      b1[u]     = (short)f2b(b10[u]);
      b1[u + 4] = (short)f2b(b11[u]);
    }
    __syncthreads();
    *(s8v*)&As[srow * 40 + scol] = a0;
    *(s8v*)&As[(srow + 64) * 40 + scol] = a1;
    *(s8v*)&Bs[srow * 40 + scol] = b0;
    *(s8v*)&Bs[(srow + 64) * 40 + scol] = b1;
    __syncthreads();
    bf8v af[4], bfr[4];
#pragma unroll
    for (int i = 0; i < 4; ++i)
      af[i] = *(const bf8v*)&As[(wm + i * 16 + fr) * 40 + fq * 8];
#pragma unroll
    for (int j = 0; j < 4; ++j)
      bfr[j] = *(const bf8v*)&Bs[(wn + j * 16 + fr) * 40 + fq * 8];
#pragma unroll
    for (int i = 0; i < 4; ++i)
#pragma unroll
      for (int j = 0; j < 4; ++j)
        acc[i][j] = __builtin_amdgcn_mfma_f32_16x16x32_bf16(af[i], bfr[j],
                                                            acc[i][j], 0, 0, 0);
  }
  float bj[4];
#pragma unroll
  for (int j = 0; j < 4; ++j) bj[j] = bias[n0 + wn + j * 16 + fr];
#pragma unroll
  for (int i = 0; i < 4; ++i) {
#pragma unroll
    for (int j = 0; j < 4; ++j) {
#pragma unroll
      for (int r = 0; r < 4; ++r) {
        int gm = m0 + wm + i * 16 + fq * 4 + r;  // D row = quad*4+reg (m89)
        int gn = n0 + wn + j * 16 + fr;          // D col = lane&15
        float v = acc[i][j][r] + bj[j];
        if (RELU) v = fmaxf(v, 0.f);
        Out[(size_t)gm * N + gn] = v;
      }
    }
  }
}

// -------------------------------------------------------- recurrence
// One block per GROUP OF 4 batch elements; 16 blocks x 1024 threads.
// Rationale (round-4 post-mortem): with 1 batch/block the weight sweep
// (Whh+Winw, ~1.3MB/step/block) never stays cache-resident (FETCH const
// 547KB/block-step across 3 structures) and every load is exposed miss
// latency (VALUBusy ~2%).  4 batches/block makes each weight load feed 4
// independent fmaf chains: 4x less weight demand, 4x more work per miss.
// Weights stay fp32 (original buffers; bf16 conversion regressed 2.1x).
__global__ __launch_bounds__(1024, 4) void k_recur(
    const float* __restrict__ gi_all,   // [32*64][768] (includes b_ih)
    const float* __restrict__ eo,       // [64][64][512] fp32
    const float* __restrict__ Whh,      // [768][256] fp32
    const float* __restrict__ bhh,      // [768]
    const float* __restrict__ Winw,     // [512][256] fp32
    const float* __restrict__ Winb,     // [512]
    ushort* __restrict__ feat,          // [32*64][768] bf16 out (GEMM A)
    float* __restrict__ hs_out) {       // [64][256] fp32 out (d_out base)
  const int b4 = blockIdx.x * 4, tid = threadIdx.x;
  __shared__ __align__(16) float h[4][256];
  __shared__ __align__(16) float q[4][512];
  __shared__ float attnp[4][64];
  __shared__ float score[4][64];

  // gh phase: hidden unit t = tid>>2, k-quarter lane p = tid&3 (interleaved);
  // lane p also owns BATCH p for the gate update.
  const int t = tid >> 2, p = tid & 3;
  const float* wr = Whh + (size_t)t * 256 + p * 4;
  const float* wz = wr + 65536;    // (t+256)*256
  const float* wn = wr + 131072;   // (t+512)*256
  const float bhr = bhh[t], bhz = bhh[t + 256], bhn = bhh[t + 512];
  const float* giT = gi_all + (size_t)(b4 + p) * 768 + t;  // batch p's gi row

  // q phase: output qo = tid>>1, k-half lane qp = tid&1 (interleaved)
  const int qo = tid >> 1, qp = tid & 1;
  const float* wq = Winw + (size_t)qo * 256 + qp * 4;
  const float qb = Winb[qo];

  // attn phase: batch ab = tid>>8, row as, k-slice ap (4 lanes/row)
  const int ab = tid >> 8, as = (tid >> 2) & 63, ap = tid & 3;
  const float* eoA = eo + (size_t)(b4 + ab) * 32768 + as * 512 + ap * 128;

  // h_star phase: batch hb = tid>>8, d-pair hd = tid&255
  const int hb = tid >> 8, hd = tid & 255;
  const float* eoH = eo + (size_t)(b4 + hb) * 32768 + 2 * hd;

  h[tid >> 8][tid & 255] = 0.f;
  __syncthreads();

  for (int st = 0; st < 32; ++st) {
    // hoist batch-p gi early (used post-reduce; latency hides under gh loop)
    float g0 = giT[(size_t)st * 49152];
    float g1 = giT[(size_t)st * 49152 + 256];
    float g2 = giT[(size_t)st * 49152 + 512];
    float hold = h[p][t];
    // ---- gh = h @ Whh.T (rows t, t+256, t+512), 4-way k-split, 4 batches.
    // Per iter: 3 weight f4v (16B, 4 lanes cover a 64B line) + 4 h f4v
    // (LDS broadcast) + 48 fmaf -> 16 fmaf per global load.
    float ar0 = 0, ar1 = 0, ar2 = 0, ar3 = 0;
    float az0 = 0, az1 = 0, az2 = 0, az3 = 0;
    float an0 = 0, an1 = 0, an2 = 0, an3 = 0;
#pragma unroll
    for (int i = 0; i < 16; ++i) {
      f4v rv = *(const f4v*)(wr + i * 16);
      f4v zv = *(const f4v*)(wz + i * 16);
      f4v nv = *(const f4v*)(wn + i * 16);
      f4v h0 = *(const f4v*)&h[0][p * 4 + i * 16];
      f4v h1 = *(const f4v*)&h[1][p * 4 + i * 16];
      f4v h2 = *(const f4v*)&h[2][p * 4 + i * 16];
      f4v h3 = *(const f4v*)&h[3][p * 4 + i * 16];
#pragma unroll
      for (int u = 0; u < 4; ++u) {
        ar0 = fmaf(h0[u], rv[u], ar0); az0 = fmaf(h0[u], zv[u], az0); an0 = fmaf(h0[u], nv[u], an0);
        ar1 = fmaf(h1[u], rv[u], ar1); az1 = fmaf(h1[u], zv[u], az1); an1 = fmaf(h1[u], nv[u], an1);
        ar2 = fmaf(h2[u], rv[u], ar2); az2 = fmaf(h2[u], zv[u], az2); an2 = fmaf(h2[u], nv[u], an2);
        ar3 = fmaf(h3[u], rv[u], ar3); az3 = fmaf(h3[u], zv[u], az3); an3 = fmaf(h3[u], nv[u], an3);
      }
    }
    // butterfly over the 4 p-lanes: every lane gets all 4 batch sums
    ar0 += __shfl_xor(ar0, 1); ar0 += __shfl_xor(ar0, 2);
    ar1 += __shfl_xor(ar1, 1); ar1 += __shfl_xor(ar1, 2);
    ar2 += __shfl_xor(ar2, 1); ar2 += __shfl_xor(ar2, 2);
    ar3 += __shfl_xor(ar3, 1); ar3 += __shfl_xor(ar3, 2);
    az0 += __shfl_xor(az0, 1); az0 += __shfl_xor(az0, 2);
    az1 += __shfl_xor(az1, 1); az1 += __shfl_xor(az1, 2);
    az2 += __shfl_xor(az2, 1); az2 += __shfl_xor(az2, 2);
    az3 += __shfl_xor(az3, 1); az3 += __shfl_xor(az3, 2);
    an0 += __shfl_xor(an0, 1); an0 += __shfl_xor(an0, 2);
    an1 += __shfl_xor(an1, 1); an1 += __shfl_xor(an1, 2);
    an2 += __shfl_xor(an2, 1); an2 += __shfl_xor(an2, 2);
    an3 += __shfl_xor(an3, 1); an3 += __shfl_xor(an3, 2);
    // lane p updates batch p (ternary select: no runtime-indexed reg array)
    float arS = p == 0 ? ar0 : p == 1 ? ar1 : p == 2 ? ar2 : ar3;
    float azS = p == 0 ? az0 : p == 1 ? az1 : p == 2 ? az2 : az3;
    float anS = p == 0 ? an0 : p == 1 ? an1 : p == 2 ? an2 : an3;
    float r = 1.f / (1.f + __expf(-(g0 + arS + bhr)));
    float z = 1.f / (1.f + __expf(-(g1 + azS + bhz)));
    float e2 = __expf(2.f * (g2 + r * (anS + bhn)));  // tanh, inf-safe
    float n = 1.f - 2.f / (e2 + 1.f);
    float hnew = (1.f - z) * n + z * hold;
    __syncthreads();               // all gh reads of h done
    h[p][t] = hnew;
    feat[((size_t)st * 64 + b4 + p) * 768 + 512 + t] = f2b(hnew);
    __syncthreads();               // h update visible
    // ---- q = h @ Winw.T + Winb, 2-way k-split, 4 batches
    float a0 = 0, a1 = 0, a2 = 0, a3 = 0;
#pragma unroll
    for (int i = 0; i < 32; ++i) {
      f4v wv = *(const f4v*)(wq + i * 8);
      f4v h0 = *(const f4v*)&h[0][qp * 4 + i * 8];
      f4v h1 = *(const f4v*)&h[1][qp * 4 + i * 8];
      f4v h2 = *(const f4v*)&h[2][qp * 4 + i * 8];
      f4v h3 = *(const f4v*)&h[3][qp * 4 + i * 8];
#pragma unroll
      for (int u = 0; u < 4; ++u) {
        a0 = fmaf(h0[u], wv[u], a0);
        a1 = fmaf(h1[u], wv[u], a1);
        a2 = fmaf(h2[u], wv[u], a2);
        a3 = fmaf(h3[u], wv[u], a3);
      }
    }
    a0 += __shfl_xor(a0, 1);
    a1 += __shfl_xor(a1, 1);
    a2 += __shfl_xor(a2, 1);
    a3 += __shfl_xor(a3, 1);
    if (qp == 0) { q[0][qo] = a0 + qb; q[2][qo] = a2 + qb; }
    else         { q[1][qo] = a1 + qb; q[3][qo] = a3 + qb; }
    __syncthreads();
    // ---- attn[b][s] = eo[b,s,:] . q[b]  — 4 lanes per (b,s), 128-elem slice
    {
      float aa0 = 0.f, aa1 = 0.f;
      const float* qv = &q[ab][ap * 128];
#pragma unroll
      for (int i = 0; i < 16; ++i) {
        f4v e0 = *(const f4v*)(eoA + i * 8);
        f4v e1 = *(const f4v*)(eoA + i * 8 + 4);
        f4v q0 = *(const f4v*)(qv + i * 8);
        f4v q1 = *(const f4v*)(qv + i * 8 + 4);
        aa0 = fmaf(e0.x, q0.x, aa0); aa0 = fmaf(e0.y, q0.y, aa0);
        aa0 = fmaf(e0.z, q0.z, aa0); aa0 = fmaf(e0.w, q0.w, aa0);
        aa1 = fmaf(e1.x, q1.x, aa1); aa1 = fmaf(e1.y, q1.y, aa1);
        aa1 = fmaf(e1.z, q1.z, aa1); aa1 = fmaf(e1.w, q1.w, aa1);
      }
      float aa = aa0 + aa1;
      aa += __shfl_xor(aa, 1); aa += __shfl_xor(aa, 2);
      if (ap == 0) attnp[ab][as] = aa;
    }
    __syncthreads();
    if (tid < 256) {  // softmax: wave w handles batch w (64 lanes = 64 s)
      float a = attnp[tid >> 6][tid & 63];
      float m = a;
#pragma unroll
      for (int off = 32; off > 0; off >>= 1) m = fmaxf(m, __shfl_xor(m, off));
      float e = __expf(a - m);
      float ss = e;
#pragma unroll
      for (int off = 32; off > 0; off >>= 1) ss += __shfl_xor(ss, off);
      score[tid >> 6][tid & 63] = e / ss;
    }
    __syncthreads();
    // ---- h_star[b][d] = sum_s score[b][s]*eo[b,s,d]; feat bf16
    {
      float s0 = 0.f, s1 = 0.f;
#pragma unroll 8
      for (int s2 = 0; s2 < 64; ++s2) {
        float sc = score[hb][s2];
        f2v ev = *(const f2v*)(eoH + (size_t)s2 * 512);
        s0 = fmaf(sc, ev.x, s0);
        s1 = fmaf(sc, ev.y, s1);
      }
      size_t row = ((size_t)st * 64 + b4 + hb) * 768;
      feat[row + 2 * hd] = f2b(s0);
      feat[row + 2 * hd + 1] = f2b(s1);
    }
    // no trailing barrier: next h write is behind next step's pre-write
    // barrier; score/attnp/q rewrites are all >=2 barriers downstream.
  }
  hs_out[(size_t)(b4 + (tid >> 8)) * 256 + (tid & 255)] = h[tid >> 8][tid & 255];
}

// ----------------------------------------------- in-place log_softmax (fp32)
// One block per (t,b) row of 32000 relu'd logits in d_out.
__global__ __launch_bounds__(256) void k_logsm(float* __restrict__ out) {
  float* p = out + (size_t)blockIdx.x * 32000;
  const int t = threadIdx.x;
  __shared__ float red[4];
  float m = 0.f;  // relu'd values are >= 0
  for (int c = t; c < 4000; c += 256) {
    f4v a = *(const f4v*)(p + (size_t)c * 8);
    f4v b = *(const f4v*)(p + (size_t)c * 8 + 4);
    m = fmaxf(m, fmaxf(fmaxf(a.x, a.y), fmaxf(a.z, a.w)));
    m = fmaxf(m, fmaxf(fmaxf(b.x, b.y), fmaxf(b.z, b.w)));
  }
#pragma unroll
  for (int off = 32; off > 0; off >>= 1) m = fmaxf(m, __shfl_xor(m, off));
  if ((t & 63) == 0) red[t >> 6] = m;
  __syncthreads();
  m = fmaxf(fmaxf(red[0], red[1]), fmaxf(red[2], red[3]));
  float s = 0.f;
  for (int c = t; c < 4000; c += 256) {
    f4v a = *(const f4v*)(p + (size_t)c * 8);
    f4v b = *(const f4v*)(p + (size_t)c * 8 + 4);
    s += __expf(a.x - m) + __expf(a.y - m) + __expf(a.z - m) + __expf(a.w - m);
    s += __expf(b.x - m) + __expf(b.y - m) + __expf(b.z - m) + __expf(b.w - m);
  }
#pragma unroll
  for (int off = 32; off > 0; off >>= 1) s += __shfl_xor(s, off);
  __syncthreads();
  if ((t & 63) == 0) red[t >> 6] = s;
  __syncthreads();
  s = red[0] + red[1] + red[2] + red[3];
  const float L = m + logf(s);
  for (int c = t; c < 4000; c += 256) {
    f4v a = *(const f4v*)(p + (size_t)c * 8);
    f4v b = *(const f4v*)(p + (size_t)c * 8 + 4);
    a.x -= L; a.y -= L; a.z -= L; a.w -= L;
    b.x -= L; b.y -= L; b.z -= L; b.w -= L;
    *(f4v*)(p + (size_t)c * 8) = a;
    *(f4v*)(p + (size_t)c * 8 + 4) = b;
  }
}

extern "C" void kernel_launch(void* const* d_in, const int* in_sizes, int n_in,
                              void* d_out, int out_size, void* d_ws, size_t ws_size,
                              hipStream_t stream) {
  (void)in_sizes; (void)n_in; (void)out_size; (void)ws_size;
  const float* target = (const float*)d_in[0];
  const float* inp    = (const float*)d_in[1];
  const float* posf   = (const float*)d_in[2];
  const float* encs   = (const float*)d_in[3];
  const float* enco   = (const float*)d_in[4];
  const float* Wih    = (const float*)d_in[5];
  const float* Whh    = (const float*)d_in[6];
  const float* bih    = (const float*)d_in[7];
  const float* bhh    = (const float*)d_in[8];
  const float* Winw   = (const float*)d_in[9];
  const float* Winb   = (const float*)d_in[10];
  const float* Woutw  = (const float*)d_in[11];
  const float* Woutb  = (const float*)d_in[12];

  char* ws = (char*)d_ws;
  ushort* X    = (ushort*)(ws);              // 2048*640  bf16 = 2.62 MB
  float*  gi   = (float*)(ws + 0x300000);    // 2048*768  fp32 = 6.29 MB
  ushort* feat = (ushort*)(ws + 0x900000);   // 2048*768  bf16 = 3.15 MB
  float* hs    = (float*)d_out;              // [16384 hs][2048*32000 logits]
  float* logits = hs + 16384;

  k_gather<<<2048, 256, 0, stream>>>(target, inp, posf, encs, X);
  k_gemm_bt<false><<<dim3(16, 6), 256, 0, stream>>>(X, Wih, bih, gi, 768, 640);
  k_recur<<<16, 1024, 0, stream>>>(gi, enco, Whh, bhh, Winw, Winb, feat, hs);
  k_gemm_bt<true><<<dim3(16, 250), 256, 0, stream>>>(feat, Woutw, Woutb, logits,
                                                     32000, 768);
  k_logsm<<<2048, 256, 0, stream>>>(logits);
}